// Round 1
// baseline (424.726 us; speedup 1.0000x reference)
//
#include <hip/hip_runtime.h>
#include <stdint.h>

#define BB 4
#define NN 4096
#define NGG 4096
#define NUU 8192

// ---------------- block-wide sum (blockDim.x == 256) -------------------
__device__ __forceinline__ float block_sum_256(float v, float* sbuf) {
#pragma unroll
  for (int o = 32; o > 0; o >>= 1) v += __shfl_down(v, o, 64);
  int lane = threadIdx.x & 63;
  int w = threadIdx.x >> 6;
  if (lane == 0) sbuf[w] = v;
  __syncthreads();
  float r = 0.f;
  if (threadIdx.x == 0) r = sbuf[0] + sbuf[1] + sbuf[2] + sbuf[3];
  __syncthreads();
  return r;
}

// ---------------- argmin over gt for each pts point --------------------
// grid (64, 8): 64 query-blocks of 256 queries, 8 candidate segments of 512.
__global__ __launch_bounds__(256) void k_argmin(const float* __restrict__ pts,
                                                const float* __restrict__ gt,
                                                unsigned long long* __restrict__ keys) {
  __shared__ float sx[512], sy[512], sz[512];
  int q = blockIdx.x * 256 + threadIdx.x;   // [0, 16384), same b per block
  int b = q >> 12;
  int seg = blockIdx.y;
  const float* gtb = gt + (size_t)b * NGG * 6 + (size_t)seg * 512 * 6;
  for (int i = threadIdx.x; i < 512; i += 256) {
    sx[i] = gtb[i * 6 + 0];
    sy[i] = gtb[i * 6 + 1];
    sz[i] = gtb[i * 6 + 2];
  }
  float qx = pts[q * 3 + 0], qy = pts[q * 3 + 1], qz = pts[q * 3 + 2];
  __syncthreads();
  float best = 3.4e38f;
  int bi = 0;
#pragma unroll 8
  for (int j = 0; j < 512; ++j) {
    float dx = qx - sx[j], dy = qy - sy[j], dz = qz - sz[j];
    float d = fmaf(dx, dx, fmaf(dy, dy, dz * dz));
    bool c = d < best;
    best = c ? d : best;
    bi = c ? j : bi;
  }
  unsigned long long key =
      ((unsigned long long)__float_as_uint(best) << 32) | (unsigned)(seg * 512 + bi);
  atomicMin(&keys[q], key);
}

// ---------------- chamfer row mins: up/offset -> gt --------------------
// grid (256, 8): queries t in [0,65536): t>>15: 0 = offset, 1 = up.
__global__ __launch_bounds__(256) void k_cham_row(const float* __restrict__ up,
                                                  const float* __restrict__ off,
                                                  const float* __restrict__ gt,
                                                  unsigned* __restrict__ rowmin) {
  __shared__ float sx[512], sy[512], sz[512];
  int t = blockIdx.x * 256 + threadIdx.x;
  int which = t >> 15;
  int r = t & 32767;            // [0, B*NU)
  int b = r >> 13;
  const float* src = (which == 0) ? off : up;
  const float* p = src + (size_t)r * 3;
  int seg = blockIdx.y;
  const float* gtb = gt + (size_t)b * NGG * 6 + (size_t)seg * 512 * 6;
  for (int i = threadIdx.x; i < 512; i += 256) {
    sx[i] = gtb[i * 6 + 0];
    sy[i] = gtb[i * 6 + 1];
    sz[i] = gtb[i * 6 + 2];
  }
  float qx = p[0], qy = p[1], qz = p[2];
  __syncthreads();
  float best = 3.4e38f;
#pragma unroll 8
  for (int j = 0; j < 512; ++j) {
    float dx = qx - sx[j], dy = qy - sy[j], dz = qz - sz[j];
    float d = fmaf(dx, dx, fmaf(dy, dy, dz * dz));
    best = fminf(best, d);
  }
  atomicMin(&rowmin[t], __float_as_uint(best));
}

// ---------------- chamfer col mins: gt -> up/offset --------------------
// grid (128, 8): queries t in [0,32768): t>>14: 0 = offset, 1 = up.
__global__ __launch_bounds__(256) void k_cham_col(const float* __restrict__ up,
                                                  const float* __restrict__ off,
                                                  const float* __restrict__ gt,
                                                  unsigned* __restrict__ colmin) {
  __shared__ float sx[1024], sy[1024], sz[1024];
  int t = blockIdx.x * 256 + threadIdx.x;
  int which = t >> 14;
  int r = t & 16383;            // [0, B*NG)
  int b = r >> 12;
  int m = r & 4095;
  const float* g = gt + (size_t)b * NGG * 6 + (size_t)m * 6;
  float qx = g[0], qy = g[1], qz = g[2];
  const float* src = (which == 0) ? off : up;
  int seg = blockIdx.y;
  const float* sb = src + (size_t)b * NUU * 3 + (size_t)seg * 1024 * 3;
  for (int i = threadIdx.x; i < 1024; i += 256) {
    sx[i] = sb[i * 3 + 0];
    sy[i] = sb[i * 3 + 1];
    sz[i] = sb[i * 3 + 2];
  }
  __syncthreads();
  float best = 3.4e38f;
#pragma unroll 8
  for (int j = 0; j < 1024; ++j) {
    float dx = qx - sx[j], dy = qy - sy[j], dz = qz - sz[j];
    float d = fmaf(dx, dx, fmaf(dy, dy, dz * dz));
    best = fminf(best, d);
  }
  atomicMin(&colmin[t], __float_as_uint(best));
}

// ------------- normalize, gather nor_gt, project; loss_nor / nor_ori ---
__global__ __launch_bounds__(256) void k_postgather(
    const float* __restrict__ ori_pre, const float* __restrict__ nor_pre,
    const float* __restrict__ gt, const unsigned long long* __restrict__ keys,
    float* __restrict__ nor_gt, float* __restrict__ ori_pro, float* __restrict__ acc) {
  __shared__ float sb1[4], sb2[4];
  int q = blockIdx.x * 256 + threadIdx.x;
  int b = q >> 12;
  float ox = ori_pre[q * 3 + 0], oy = ori_pre[q * 3 + 1], oz = ori_pre[q * 3 + 2];
  float n1 = sqrtf(fmaf(ox, ox, fmaf(oy, oy, oz * oz)) + 1e-8f) + 1e-10f;
  ox /= n1; oy /= n1; oz /= n1;
  float px = nor_pre[q * 3 + 0], py = nor_pre[q * 3 + 1], pz = nor_pre[q * 3 + 2];
  float n2 = sqrtf(fmaf(px, px, fmaf(py, py, pz * pz)) + 1e-8f) + 1e-10f;
  px /= n2; py /= n2; pz /= n2;
  unsigned idx = (unsigned)(keys[q] & 0xffffffffULL);
  const float* g = gt + (size_t)b * NGG * 6 + (size_t)idx * 6 + 3;
  float gx = g[0], gy = g[1], gz = g[2];
  float dn = fmaf(gx, ox, fmaf(gy, oy, gz * oz));
  float vx = ox - gx * dn, vy = oy - gy * dn, vz = oz - gz * dn;
  float n3 = sqrtf(fmaf(vx, vx, fmaf(vy, vy, vz * vz)) + 1e-8f) + 1e-10f;
  vx /= n3; vy /= n3; vz /= n3;
  nor_gt[q * 3 + 0] = gx; nor_gt[q * 3 + 1] = gy; nor_gt[q * 3 + 2] = gz;
  ori_pro[q * 3 + 0] = vx; ori_pro[q * 3 + 1] = vy; ori_pro[q * 3 + 2] = vz;
  // loss_nor term: 1 - |cossim(nor_gt, nor_pre_n)|
  float na = fmaxf(sqrtf(fmaf(gx, gx, fmaf(gy, gy, gz * gz))), 1e-8f);
  float nb = fmaxf(sqrtf(fmaf(px, px, fmaf(py, py, pz * pz))), 1e-8f);
  float cs = fmaf(gx, px, fmaf(gy, py, gz * pz)) / (na * nb);
  float t_nor = 1.f - fabsf(cs);
  float t_ori = fabsf(dn);
  float s1 = block_sum_256(t_nor, sb1);
  float s2 = block_sum_256(t_ori, sb2);
  if (threadIdx.x == 0) {
    atomicAdd(&acc[1], s1);
    atomicAdd(&acc[2], s2);
  }
}

// ------------- KNN (K=6) among pts + fused loss_smooth -----------------
// grid (512): 32 queries/block, 8 threads/query, interleaved candidates.
__global__ __launch_bounds__(256) void k_knn_smooth(const float* __restrict__ pts,
                                                    const float* __restrict__ nor_gt,
                                                    const float* __restrict__ ori_pro,
                                                    float* __restrict__ acc) {
  __shared__ float sx[4096], sy[4096], sz[4096];          // 48 KB
  __shared__ unsigned long long marr[32 * 48];            // 12 KB
  __shared__ float sbuf[4];
  int q_local = threadIdx.x >> 3;
  int t = threadIdx.x & 7;
  int q = blockIdx.x * 32 + q_local;
  int b = q >> 12;
  int n = q & 4095;
  const float* pb = pts + (size_t)b * NN * 3;
  for (int p = threadIdx.x; p < 4096; p += 256) {
    sx[p] = pb[p * 3 + 0];
    sy[p] = pb[p * 3 + 1];
    sz[p] = pb[p * 3 + 2];
  }
  __syncthreads();
  float qx = sx[n], qy = sy[n], qz = sz[n];
  unsigned long long k0 = ~0ULL, k1 = ~0ULL, k2 = ~0ULL,
                     k3 = ~0ULL, k4 = ~0ULL, k5 = ~0ULL;
  for (int j = 0; j < 512; ++j) {
    int c = (j << 3) | t;    // interleaved: conflict-free 8-way LDS broadcast
    float dx = qx - sx[c], dy = qy - sy[c], dz = qz - sz[c];
    float d = fmaf(dx, dx, fmaf(dy, dy, dz * dz));
    unsigned long long cand =
        ((unsigned long long)__float_as_uint(d) << 32) | (unsigned)c;
    if (cand < k5) {
      bool cc; unsigned long long mn;
      cc = cand < k0; mn = cc ? cand : k0; cand = cc ? k0 : cand; k0 = mn;
      cc = cand < k1; mn = cc ? cand : k1; cand = cc ? k1 : cand; k1 = mn;
      cc = cand < k2; mn = cc ? cand : k2; cand = cc ? k2 : cand; k2 = mn;
      cc = cand < k3; mn = cc ? cand : k3; cand = cc ? k3 : cand; k3 = mn;
      cc = cand < k4; mn = cc ? cand : k4; cand = cc ? k4 : cand; k4 = mn;
      cc = cand < k5; mn = cc ? cand : k5; cand = cc ? k5 : cand; k5 = mn;
    }
  }
  unsigned long long* mq = &marr[q_local * 48 + t * 6];
  mq[0] = k0; mq[1] = k1; mq[2] = k2; mq[3] = k3; mq[4] = k4; mq[5] = k5;
  __syncthreads();
  float sum = 0.f;
  if (t == 0) {
    float ngx = nor_gt[q * 3 + 0], ngy = nor_gt[q * 3 + 1], ngz = nor_gt[q * 3 + 2];
    float box = ori_pro[q * 3 + 0], boy = ori_pro[q * 3 + 1], boz = ori_pro[q * 3 + 2];
    float rx = boy * ngz - boz * ngy;
    float ry = boz * ngx - box * ngz;
    float rz = box * ngy - boy * ngx;
    float nbo = fmaxf(sqrtf(fmaf(box, box, fmaf(boy, boy, boz * boz))), 1e-8f);
    float nrot = fmaxf(sqrtf(fmaf(rx, rx, fmaf(ry, ry, rz * rz))), 1e-8f);
    const unsigned long long* mrow = &marr[q_local * 48];
    unsigned long long last = 0;
    bool first = true;
    for (int k = 0; k < 6; ++k) {
      unsigned long long best = ~0ULL;
      for (int i = 0; i < 48; ++i) {
        unsigned long long v = mrow[i];
        if ((first || v > last) && v < best) best = v;
      }
      first = false;
      last = best;
      int id = (int)(best & 0xffffffffULL);
      const float* gn = &nor_gt[(size_t)(b * 4096 + id) * 3];
      const float* go = &ori_pro[(size_t)(b * 4096 + id) * 3];
      float gnx = gn[0], gny = gn[1], gnz = gn[2];
      float gox = go[0], goy = go[1], goz = go[2];
      float nd = fmaf(gnx, ngx, fmaf(gny, ngy, gnz * ngz));
      float wv = (expf(-nd / 0.3f) * 10.f + 1.f) < 4.f ? 1.f : 5.f;
      float ngo = fmaxf(sqrtf(fmaf(gox, gox, fmaf(goy, goy, goz * goz))), 1e-8f);
      float c0 = fmaf(gox, box, fmaf(goy, boy, goz * boz)) / (ngo * nbo);
      float c1 = fmaf(gox, rx, fmaf(goy, ry, goz * rz)) / (ngo * nrot);
      float cosv = fminf(1.f - fabsf(c0), 1.f - fabsf(c1));
      sum += wv * cosv;
    }
  }
  float s = block_sum_256(sum, sbuf);
  if (threadIdx.x == 0) atomicAdd(&acc[0], s);
}

// ------------- sum the row/col min arrays into accumulators ------------
// grid (384): blocks 0..255 -> rowmin[65536], 256..383 -> colmin[32768]
__global__ __launch_bounds__(256) void k_reduce_mins(const unsigned* __restrict__ rowmin,
                                                     const unsigned* __restrict__ colmin,
                                                     float* __restrict__ acc) {
  __shared__ float sbuf[4];
  int blk = blockIdx.x;
  float v;
  int slot;
  if (blk < 256) {
    int i = blk * 256 + threadIdx.x;
    v = __uint_as_float(rowmin[i]);
    slot = (i >> 15) ? 5 : 3;   // 0=offset rows -> acc3, 1=up rows -> acc5
  } else {
    int i = (blk - 256) * 256 + threadIdx.x;
    v = __uint_as_float(colmin[i]);
    slot = (i >> 14) ? 6 : 4;   // 0=offset cols -> acc4, 1=up cols -> acc6
  }
  float s = block_sum_256(v, sbuf);
  if (threadIdx.x == 0) atomicAdd(&acc[slot], s);
}

// ------------- combine to the 7 outputs --------------------------------
__global__ void k_finalize(const float* __restrict__ acc, float* __restrict__ out) {
  if (threadIdx.x == 0 && blockIdx.x == 0) {
    float loss_smooth = acc[0] / 98304.f;            // B*N*K
    float loss_nor = acc[1] / 16384.f;               // B*N
    float loss_nor_ori = acc[2] / 16384.f;
    float lco = acc[3] / 32768.f + acc[4] / 16384.f; // B*NU rows + B*NG cols
    float lc = acc[5] / 32768.f + acc[6] / 16384.f;
    float loss_cd = lc + 0.4f * lco;
    float loss = loss_smooth + loss_nor + 0.1f * loss_nor_ori + 200.f * loss_cd;
    out[0] = loss;
    out[1] = loss_smooth;
    out[2] = loss_nor;
    out[3] = lco;
    out[4] = loss_nor_ori;
    out[5] = lc;
    out[6] = lc;
  }
}

extern "C" void kernel_launch(void* const* d_in, const int* in_sizes, int n_in,
                              void* d_out, int out_size, void* d_ws, size_t ws_size,
                              hipStream_t stream) {
  (void)in_sizes; (void)n_in; (void)out_size; (void)ws_size;
  const float* ori_pre = (const float*)d_in[0];
  const float* nor_pre = (const float*)d_in[1];
  const float* xyz_up = (const float*)d_in[2];
  const float* xyz_off = (const float*)d_in[3];
  const float* pts = (const float*)d_in[4];
  const float* gt = (const float*)d_in[5];
  float* out = (float*)d_out;
  char* ws = (char*)d_ws;

  float* acc = (float*)(ws + 0);                                   // 16 floats
  unsigned long long* keys = (unsigned long long*)(ws + 512);      // 16384 u64 = 128 KB
  unsigned* rowmin = (unsigned*)(ws + 512 + 131072);               // 65536 u32 = 256 KB
  unsigned* colmin = (unsigned*)(ws + 512 + 131072 + 262144);      // 32768 u32 = 128 KB
  float* nor_gt = (float*)(ws + 512 + 131072 + 262144 + 131072);   // 49152 f32 = 192 KB
  float* ori_pro = (float*)(ws + 512 + 131072 + 262144 + 131072 + 196608);

  hipMemsetAsync(acc, 0, 64, stream);
  hipMemsetAsync(ws + 512, 0xFF, 131072 + 262144 + 131072, stream);

  k_argmin<<<dim3(64, 8), 256, 0, stream>>>(pts, gt, keys);
  k_cham_row<<<dim3(256, 8), 256, 0, stream>>>(xyz_up, xyz_off, gt, rowmin);
  k_cham_col<<<dim3(128, 8), 256, 0, stream>>>(xyz_up, xyz_off, gt, colmin);
  k_postgather<<<64, 256, 0, stream>>>(ori_pre, nor_pre, gt, keys, nor_gt, ori_pro, acc);
  k_knn_smooth<<<512, 256, 0, stream>>>(pts, nor_gt, ori_pro, acc);
  k_reduce_mins<<<384, 256, 0, stream>>>(rowmin, colmin, acc);
  k_finalize<<<1, 64, 0, stream>>>(acc, out);
}

// Round 2
// 384.702 us; speedup vs baseline: 1.1040x; 1.1040x over previous
//
#include <hip/hip_runtime.h>
#include <stdint.h>

#define BB 4
#define NN 4096
#define NGG 4096
#define NUU 8192

// monotone float->uint mapping (order-preserving incl. negatives)
__device__ __forceinline__ unsigned fkey32(float f) {
  unsigned u = __float_as_uint(f);
  return u ^ (((int)u >> 31) | 0x80000000u);
}
__device__ __forceinline__ float unfkey32(unsigned k) {
  unsigned m = (k & 0x80000000u) ? 0x80000000u : 0xFFFFFFFFu;
  return __uint_as_float(k ^ m);
}

// ---------------- block-wide sum (blockDim.x == 256) -------------------
__device__ __forceinline__ float block_sum_256(float v, float* sbuf) {
#pragma unroll
  for (int o = 32; o > 0; o >>= 1) v += __shfl_down(v, o, 64);
  int lane = threadIdx.x & 63;
  int w = threadIdx.x >> 6;
  if (lane == 0) sbuf[w] = v;
  __syncthreads();
  float r = 0.f;
  if (threadIdx.x == 0) r = sbuf[0] + sbuf[1] + sbuf[2] + sbuf[3];
  __syncthreads();
  return r;
}

// ---------------- argmin over gt for each pts point --------------------
// grid (64, 8): 64 query-blocks of 256 queries, 8 candidate segments of 512.
__global__ __launch_bounds__(256) void k_argmin(const float* __restrict__ pts,
                                                const float* __restrict__ gt,
                                                unsigned long long* __restrict__ keys) {
  __shared__ float4 sc[512];   // 8 KB
  int q = blockIdx.x * 256 + threadIdx.x;   // [0, 16384), same b per block
  int b = q >> 12;
  int seg = blockIdx.y;
  const float* gtb = gt + (size_t)b * NGG * 6 + (size_t)seg * 512 * 6;
  for (int i = threadIdx.x; i < 512; i += 256) {
    float x = gtb[i * 6 + 0], y = gtb[i * 6 + 1], z = gtb[i * 6 + 2];
    sc[i] = make_float4(x, y, z, fmaf(x, x, fmaf(y, y, z * z)));
  }
  float qx = pts[q * 3 + 0], qy = pts[q * 3 + 1], qz = pts[q * 3 + 2];
  float qx2 = -2.f * qx, qy2 = -2.f * qy, qz2 = -2.f * qz;
  __syncthreads();
  float best = 3.4e38f;
  int bi = 0;
#pragma unroll 8
  for (int j = 0; j < 512; ++j) {
    float4 c = sc[j];
    float d = fmaf(c.x, qx2, c.w);
    d = fmaf(c.y, qy2, d);
    d = fmaf(c.z, qz2, d);
    bool cc = d < best;
    best = cc ? d : best;
    bi = cc ? j : bi;
  }
  unsigned long long key =
      ((unsigned long long)fkey32(best) << 32) | (unsigned)(seg * 512 + bi);
  atomicMin(&keys[q], key);
}

// ---------------- chamfer row mins: up/offset -> gt --------------------
// grid (256, 8): queries t in [0,65536): t>>15: 0 = offset, 1 = up.
__global__ __launch_bounds__(256) void k_cham_row(const float* __restrict__ up,
                                                  const float* __restrict__ off,
                                                  const float* __restrict__ gt,
                                                  unsigned* __restrict__ rowmin) {
  __shared__ float4 sc[512];   // 8 KB
  int t = blockIdx.x * 256 + threadIdx.x;
  int which = t >> 15;                 // uniform per block
  int r = t & 32767;                   // [0, B*NU)
  int b = r >> 13;                     // uniform per block
  const float* src = (which == 0) ? off : up;
  const float* p = src + (size_t)r * 3;
  int seg = blockIdx.y;
  const float* gtb = gt + (size_t)b * NGG * 6 + (size_t)seg * 512 * 6;
  for (int i = threadIdx.x; i < 512; i += 256) {
    float x = gtb[i * 6 + 0], y = gtb[i * 6 + 1], z = gtb[i * 6 + 2];
    sc[i] = make_float4(x, y, z, fmaf(x, x, fmaf(y, y, z * z)));
  }
  float qx = p[0], qy = p[1], qz = p[2];
  float qq = fmaf(qx, qx, fmaf(qy, qy, qz * qz));
  float qx2 = -2.f * qx, qy2 = -2.f * qy, qz2 = -2.f * qz;
  __syncthreads();
  float best = 3.4e38f;
#pragma unroll 8
  for (int j = 0; j < 512; ++j) {
    float4 c = sc[j];
    float d = fmaf(c.x, qx2, c.w);
    d = fmaf(c.y, qy2, d);
    d = fmaf(c.z, qz2, d);
    best = fminf(best, d);
  }
  atomicMin(&rowmin[t], fkey32(best + qq));
}

// ---------------- chamfer col mins: gt -> up/offset --------------------
// grid (128, 8): queries t in [0,32768): t>>14: 0 = offset, 1 = up.
__global__ __launch_bounds__(256) void k_cham_col(const float* __restrict__ up,
                                                  const float* __restrict__ off,
                                                  const float* __restrict__ gt,
                                                  unsigned* __restrict__ colmin) {
  __shared__ float4 sc[1024];  // 16 KB
  int t = blockIdx.x * 256 + threadIdx.x;
  int which = t >> 14;                 // uniform per block
  int r = t & 16383;                   // [0, B*NG)
  int b = r >> 12;                     // uniform per block
  int m = r & 4095;
  const float* g = gt + (size_t)b * NGG * 6 + (size_t)m * 6;
  float qx = g[0], qy = g[1], qz = g[2];
  float qq = fmaf(qx, qx, fmaf(qy, qy, qz * qz));
  float qx2 = -2.f * qx, qy2 = -2.f * qy, qz2 = -2.f * qz;
  const float* src = (which == 0) ? off : up;
  int seg = blockIdx.y;
  const float* sb = src + (size_t)b * NUU * 3 + (size_t)seg * 1024 * 3;
  for (int i = threadIdx.x; i < 1024; i += 256) {
    float x = sb[i * 3 + 0], y = sb[i * 3 + 1], z = sb[i * 3 + 2];
    sc[i] = make_float4(x, y, z, fmaf(x, x, fmaf(y, y, z * z)));
  }
  __syncthreads();
  float best = 3.4e38f;
#pragma unroll 8
  for (int j = 0; j < 1024; ++j) {
    float4 c = sc[j];
    float d = fmaf(c.x, qx2, c.w);
    d = fmaf(c.y, qy2, d);
    d = fmaf(c.z, qz2, d);
    best = fminf(best, d);
  }
  atomicMin(&colmin[t], fkey32(best + qq));
}

// ------------- normalize, gather nor_gt, project; loss_nor / nor_ori ---
__global__ __launch_bounds__(256) void k_postgather(
    const float* __restrict__ ori_pre, const float* __restrict__ nor_pre,
    const float* __restrict__ gt, const unsigned long long* __restrict__ keys,
    float* __restrict__ nor_gt, float* __restrict__ ori_pro, float* __restrict__ acc) {
  __shared__ float sb1[4], sb2[4];
  int q = blockIdx.x * 256 + threadIdx.x;
  int b = q >> 12;
  float ox = ori_pre[q * 3 + 0], oy = ori_pre[q * 3 + 1], oz = ori_pre[q * 3 + 2];
  float n1 = sqrtf(fmaf(ox, ox, fmaf(oy, oy, oz * oz)) + 1e-8f) + 1e-10f;
  ox /= n1; oy /= n1; oz /= n1;
  float px = nor_pre[q * 3 + 0], py = nor_pre[q * 3 + 1], pz = nor_pre[q * 3 + 2];
  float n2 = sqrtf(fmaf(px, px, fmaf(py, py, pz * pz)) + 1e-8f) + 1e-10f;
  px /= n2; py /= n2; pz /= n2;
  unsigned idx = (unsigned)(keys[q] & 0xffffffffULL);
  const float* g = gt + (size_t)b * NGG * 6 + (size_t)idx * 6 + 3;
  float gx = g[0], gy = g[1], gz = g[2];
  float dn = fmaf(gx, ox, fmaf(gy, oy, gz * oz));
  float vx = ox - gx * dn, vy = oy - gy * dn, vz = oz - gz * dn;
  float n3 = sqrtf(fmaf(vx, vx, fmaf(vy, vy, vz * vz)) + 1e-8f) + 1e-10f;
  vx /= n3; vy /= n3; vz /= n3;
  nor_gt[q * 3 + 0] = gx; nor_gt[q * 3 + 1] = gy; nor_gt[q * 3 + 2] = gz;
  ori_pro[q * 3 + 0] = vx; ori_pro[q * 3 + 1] = vy; ori_pro[q * 3 + 2] = vz;
  float na = fmaxf(sqrtf(fmaf(gx, gx, fmaf(gy, gy, gz * gz))), 1e-8f);
  float nb = fmaxf(sqrtf(fmaf(px, px, fmaf(py, py, pz * pz))), 1e-8f);
  float cs = fmaf(gx, px, fmaf(gy, py, gz * pz)) / (na * nb);
  float t_nor = 1.f - fabsf(cs);
  float t_ori = fabsf(dn);
  float s1 = block_sum_256(t_nor, sb1);
  float s2 = block_sum_256(t_ori, sb2);
  if (threadIdx.x == 0) {
    atomicAdd(&acc[1], s1);
    atomicAdd(&acc[2], s2);
  }
}

// ------------- KNN (K=6) among pts + fused loss_smooth -----------------
// grid (512): 32 queries/block, 8 threads/query, interleaved candidates.
__global__ __launch_bounds__(256) void k_knn_smooth(const float* __restrict__ pts,
                                                    const float* __restrict__ nor_gt,
                                                    const float* __restrict__ ori_pro,
                                                    float* __restrict__ acc) {
  __shared__ float4 sp[4096];                             // 64 KB
  __shared__ unsigned long long marr[32 * 48];            // 12 KB
  __shared__ float sbuf[4];
  int q_local = threadIdx.x >> 3;
  int t = threadIdx.x & 7;
  int q = blockIdx.x * 32 + q_local;
  int b = q >> 12;
  int n = q & 4095;
  const float* pb = pts + (size_t)b * NN * 3;
  for (int p = threadIdx.x; p < 4096; p += 256) {
    float x = pb[p * 3 + 0], y = pb[p * 3 + 1], z = pb[p * 3 + 2];
    sp[p] = make_float4(x, y, z, fmaf(x, x, fmaf(y, y, z * z)));
  }
  __syncthreads();
  float4 qp = sp[n];
  float qx2 = -2.f * qp.x, qy2 = -2.f * qp.y, qz2 = -2.f * qp.z;
  float d0 = 3.4e38f, d1 = 3.4e38f, d2 = 3.4e38f,
        d3 = 3.4e38f, d4 = 3.4e38f, d5 = 3.4e38f;
  int i0 = 0, i1 = 0, i2 = 0, i3 = 0, i4 = 0, i5 = 0;
#pragma unroll 4
  for (int j = 0; j < 512; ++j) {
    int c = (j << 3) | t;    // interleaved: 8-lane-contiguous + broadcast
    float4 p = sp[c];
    float d = fmaf(p.x, qx2, p.w);
    d = fmaf(p.y, qy2, d);
    d = fmaf(p.z, qz2, d);
    if (d < d5) {            // rare: sorted insertion of (d, c)
      int ci = c;
      bool cc; float nd; int ni;
      cc = d < d0; nd = cc ? d : d0; d = cc ? d0 : d; ni = cc ? ci : i0; ci = cc ? i0 : ci; d0 = nd; i0 = ni;
      cc = d < d1; nd = cc ? d : d1; d = cc ? d1 : d; ni = cc ? ci : i1; ci = cc ? i1 : ci; d1 = nd; i1 = ni;
      cc = d < d2; nd = cc ? d : d2; d = cc ? d2 : d; ni = cc ? ci : i2; ci = cc ? i2 : ci; d2 = nd; i2 = ni;
      cc = d < d3; nd = cc ? d : d3; d = cc ? d3 : d; ni = cc ? ci : i3; ci = cc ? i3 : ci; d3 = nd; i3 = ni;
      cc = d < d4; nd = cc ? d : d4; d = cc ? d4 : d; ni = cc ? ci : i4; ci = cc ? i4 : ci; d4 = nd; i4 = ni;
      cc = d < d5; nd = cc ? d : d5;                    ni = cc ? ci : i5;                  d5 = nd; i5 = ni;
    }
  }
  unsigned long long* mq = &marr[q_local * 48 + t * 6];
  mq[0] = ((unsigned long long)fkey32(d0) << 32) | (unsigned)i0;
  mq[1] = ((unsigned long long)fkey32(d1) << 32) | (unsigned)i1;
  mq[2] = ((unsigned long long)fkey32(d2) << 32) | (unsigned)i2;
  mq[3] = ((unsigned long long)fkey32(d3) << 32) | (unsigned)i3;
  mq[4] = ((unsigned long long)fkey32(d4) << 32) | (unsigned)i4;
  mq[5] = ((unsigned long long)fkey32(d5) << 32) | (unsigned)i5;
  __syncthreads();
  float sum = 0.f;
  if (t == 0) {
    float ngx = nor_gt[q * 3 + 0], ngy = nor_gt[q * 3 + 1], ngz = nor_gt[q * 3 + 2];
    float box = ori_pro[q * 3 + 0], boy = ori_pro[q * 3 + 1], boz = ori_pro[q * 3 + 2];
    float rx = boy * ngz - boz * ngy;
    float ry = boz * ngx - box * ngz;
    float rz = box * ngy - boy * ngx;
    float nbo = fmaxf(sqrtf(fmaf(box, box, fmaf(boy, boy, boz * boz))), 1e-8f);
    float nrot = fmaxf(sqrtf(fmaf(rx, rx, fmaf(ry, ry, rz * rz))), 1e-8f);
    const unsigned long long* mrow = &marr[q_local * 48];
    int head[8] = {0, 0, 0, 0, 0, 0, 0, 0};
    for (int k = 0; k < 6; ++k) {
      // 8-way merge of sorted per-thread lists: pick global min of heads
      unsigned long long best = ~0ULL;
      int bl = 0;
#pragma unroll
      for (int l = 0; l < 8; ++l) {
        unsigned long long v = mrow[l * 6 + head[l]];
        if (v < best) { best = v; bl = l; }
      }
#pragma unroll
      for (int l = 0; l < 8; ++l) head[l] += (l == bl) ? 1 : 0;
      int id = (int)(best & 0xffffffffULL);
      const float* gn = &nor_gt[(size_t)(b * 4096 + id) * 3];
      const float* go = &ori_pro[(size_t)(b * 4096 + id) * 3];
      float gnx = gn[0], gny = gn[1], gnz = gn[2];
      float gox = go[0], goy = go[1], goz = go[2];
      float nd = fmaf(gnx, ngx, fmaf(gny, ngy, gnz * ngz));
      float wv = (expf(-nd / 0.3f) * 10.f + 1.f) < 4.f ? 1.f : 5.f;
      float ngo = fmaxf(sqrtf(fmaf(gox, gox, fmaf(goy, goy, goz * goz))), 1e-8f);
      float c0 = fmaf(gox, box, fmaf(goy, boy, goz * boz)) / (ngo * nbo);
      float c1 = fmaf(gox, rx, fmaf(goy, ry, goz * rz)) / (ngo * nrot);
      float cosv = fminf(1.f - fabsf(c0), 1.f - fabsf(c1));
      sum += wv * cosv;
    }
  }
  float s = block_sum_256(sum, sbuf);
  if (threadIdx.x == 0) atomicAdd(&acc[0], s);
}

// ------------- sum the row/col min arrays into accumulators ------------
// grid (384): blocks 0..255 -> rowmin[65536], 256..383 -> colmin[32768]
__global__ __launch_bounds__(256) void k_reduce_mins(const unsigned* __restrict__ rowmin,
                                                     const unsigned* __restrict__ colmin,
                                                     float* __restrict__ acc) {
  __shared__ float sbuf[4];
  int blk = blockIdx.x;
  float v;
  int slot;
  if (blk < 256) {
    int i = blk * 256 + threadIdx.x;
    v = unfkey32(rowmin[i]);
    slot = (i >> 15) ? 5 : 3;   // 0=offset rows -> acc3, 1=up rows -> acc5
  } else {
    int i = (blk - 256) * 256 + threadIdx.x;
    v = unfkey32(colmin[i]);
    slot = (i >> 14) ? 6 : 4;   // 0=offset cols -> acc4, 1=up cols -> acc6
  }
  float s = block_sum_256(v, sbuf);
  if (threadIdx.x == 0) atomicAdd(&acc[slot], s);
}

// ------------- combine to the 7 outputs --------------------------------
__global__ void k_finalize(const float* __restrict__ acc, float* __restrict__ out) {
  if (threadIdx.x == 0 && blockIdx.x == 0) {
    float loss_smooth = acc[0] / 98304.f;            // B*N*K
    float loss_nor = acc[1] / 16384.f;               // B*N
    float loss_nor_ori = acc[2] / 16384.f;
    float lco = acc[3] / 32768.f + acc[4] / 16384.f; // B*NU rows + B*NG cols
    float lc = acc[5] / 32768.f + acc[6] / 16384.f;
    float loss_cd = lc + 0.4f * lco;
    float loss = loss_smooth + loss_nor + 0.1f * loss_nor_ori + 200.f * loss_cd;
    out[0] = loss;
    out[1] = loss_smooth;
    out[2] = loss_nor;
    out[3] = lco;
    out[4] = loss_nor_ori;
    out[5] = lc;
    out[6] = lc;
  }
}

extern "C" void kernel_launch(void* const* d_in, const int* in_sizes, int n_in,
                              void* d_out, int out_size, void* d_ws, size_t ws_size,
                              hipStream_t stream) {
  (void)in_sizes; (void)n_in; (void)out_size; (void)ws_size;
  const float* ori_pre = (const float*)d_in[0];
  const float* nor_pre = (const float*)d_in[1];
  const float* xyz_up = (const float*)d_in[2];
  const float* xyz_off = (const float*)d_in[3];
  const float* pts = (const float*)d_in[4];
  const float* gt = (const float*)d_in[5];
  float* out = (float*)d_out;
  char* ws = (char*)d_ws;

  float* acc = (float*)(ws + 0);                                   // 16 floats
  unsigned long long* keys = (unsigned long long*)(ws + 512);      // 16384 u64 = 128 KB
  unsigned* rowmin = (unsigned*)(ws + 512 + 131072);               // 65536 u32 = 256 KB
  unsigned* colmin = (unsigned*)(ws + 512 + 131072 + 262144);      // 32768 u32 = 128 KB
  float* nor_gt = (float*)(ws + 512 + 131072 + 262144 + 131072);   // 49152 f32 = 192 KB
  float* ori_pro = (float*)(ws + 512 + 131072 + 262144 + 131072 + 196608);

  hipMemsetAsync(acc, 0, 64, stream);
  hipMemsetAsync(ws + 512, 0xFF, 131072 + 262144 + 131072, stream);

  k_argmin<<<dim3(64, 8), 256, 0, stream>>>(pts, gt, keys);
  k_cham_row<<<dim3(256, 8), 256, 0, stream>>>(xyz_up, xyz_off, gt, rowmin);
  k_cham_col<<<dim3(128, 8), 256, 0, stream>>>(xyz_up, xyz_off, gt, colmin);
  k_postgather<<<64, 256, 0, stream>>>(ori_pre, nor_pre, gt, keys, nor_gt, ori_pro, acc);
  k_knn_smooth<<<512, 256, 0, stream>>>(pts, nor_gt, ori_pro, acc);
  k_reduce_mins<<<384, 256, 0, stream>>>(rowmin, colmin, acc);
  k_finalize<<<1, 64, 0, stream>>>(acc, out);
}

// Round 3
// 221.528 us; speedup vs baseline: 1.9173x; 1.7366x over previous
//
#include <hip/hip_runtime.h>
#include <stdint.h>

#define NN 4096
#define NGG 4096
#define NUU 8192

// monotone float->uint mapping (order-preserving incl. negatives)
__device__ __forceinline__ unsigned fkey32(float f) {
  unsigned u = __float_as_uint(f);
  return u ^ (((int)u >> 31) | 0x80000000u);
}
__device__ __forceinline__ float unfkey32(unsigned k) {
  unsigned m = (k & 0x80000000u) ? 0x80000000u : 0xFFFFFFFFu;
  return __uint_as_float(k ^ m);
}

// ---------------- block-wide sum (blockDim.x == 256) -------------------
__device__ __forceinline__ float block_sum_256(float v, float* sbuf) {
#pragma unroll
  for (int o = 32; o > 0; o >>= 1) v += __shfl_down(v, o, 64);
  int lane = threadIdx.x & 63;
  int w = threadIdx.x >> 6;
  if (lane == 0) sbuf[w] = v;
  __syncthreads();
  float r = 0.f;
  if (threadIdx.x == 0) r = sbuf[0] + sbuf[1] + sbuf[2] + sbuf[3];
  __syncthreads();
  return r;
}

// ---------------- fused scan: argmin + chamfer rows + chamfer cols -----
// Q=4 queries/thread: one ds_read_b128 per candidate serves 4 pair-evals.
// blocks [0,512): cham_row  (65536 queries, gt candidates, 8 segs x 512)
// blocks [512,1024): cham_col (32768 queries, up/off candidates, 16 segs x 512)
// blocks [1024,1280): argmin (16384 queries, gt candidates, 16 segs x 256)
__global__ __launch_bounds__(256) void k_scan(const float* __restrict__ pts,
                                              const float* __restrict__ gt,
                                              const float* __restrict__ up,
                                              const float* __restrict__ off,
                                              unsigned long long* __restrict__ keys,
                                              unsigned* __restrict__ rowmin,
                                              unsigned* __restrict__ colmin) {
  __shared__ float4 sc[512];   // 8 KB
  int blk = blockIdx.x;
  int tid = threadIdx.x;

  if (blk < 512) {
    // ------- cham_row: up/off points vs gt candidates -------
    int qb = blk >> 3;           // [0,64)
    int seg = blk & 7;           // [0,8)
    int wb = qb >> 3;            // [0,8)
    int which = wb >> 2;         // 0=off, 1=up
    int b = wb & 3;
    int r0 = (qb & 7) * 1024 + tid * 4;   // [0,8192)
    {
      const float* gtb = gt + (size_t)b * NGG * 6 + (size_t)seg * 512 * 6;
      int i0 = tid * 2;
      const float4* g4 = (const float4*)(gtb + (size_t)i0 * 6);
      float4 u0 = g4[0], u1 = g4[1], u2 = g4[2];
      sc[i0] = make_float4(u0.x, u0.y, u0.z,
                           fmaf(u0.x, u0.x, fmaf(u0.y, u0.y, u0.z * u0.z)));
      sc[i0 + 1] = make_float4(u1.z, u1.w, u2.x,
                               fmaf(u1.z, u1.z, fmaf(u1.w, u1.w, u2.x * u2.x)));
    }
    const float* src = which ? up : off;
    const float4* s4 = (const float4*)src;
    size_t fb = ((size_t)(b * NUU + r0) * 3) >> 2;
    float4 A = s4[fb], B = s4[fb + 1], C = s4[fb + 2];
    float q0x = A.x, q0y = A.y, q0z = A.z;
    float q1x = A.w, q1y = B.x, q1z = B.y;
    float q2x = B.z, q2y = B.w, q2z = C.x;
    float q3x = C.y, q3y = C.z, q3z = C.w;
    float qq0 = fmaf(q0x, q0x, fmaf(q0y, q0y, q0z * q0z));
    float qq1 = fmaf(q1x, q1x, fmaf(q1y, q1y, q1z * q1z));
    float qq2 = fmaf(q2x, q2x, fmaf(q2y, q2y, q2z * q2z));
    float qq3 = fmaf(q3x, q3x, fmaf(q3y, q3y, q3z * q3z));
    float a0x = -2.f * q0x, a0y = -2.f * q0y, a0z = -2.f * q0z;
    float a1x = -2.f * q1x, a1y = -2.f * q1y, a1z = -2.f * q1z;
    float a2x = -2.f * q2x, a2y = -2.f * q2y, a2z = -2.f * q2z;
    float a3x = -2.f * q3x, a3y = -2.f * q3y, a3z = -2.f * q3z;
    __syncthreads();
    float b0 = 3.4e38f, b1 = 3.4e38f, b2 = 3.4e38f, b3 = 3.4e38f;
#pragma unroll 4
    for (int j = 0; j < 512; ++j) {
      float4 c = sc[j];
      float t;
      t = fmaf(c.x, a0x, c.w); t = fmaf(c.y, a0y, t); t = fmaf(c.z, a0z, t); b0 = fminf(b0, t);
      t = fmaf(c.x, a1x, c.w); t = fmaf(c.y, a1y, t); t = fmaf(c.z, a1z, t); b1 = fminf(b1, t);
      t = fmaf(c.x, a2x, c.w); t = fmaf(c.y, a2y, t); t = fmaf(c.z, a2z, t); b2 = fminf(b2, t);
      t = fmaf(c.x, a3x, c.w); t = fmaf(c.y, a3y, t); t = fmaf(c.z, a3z, t); b3 = fminf(b3, t);
    }
    int gr = which * 32768 + b * NUU + r0;
    atomicMin(&rowmin[gr + 0], fkey32(b0 + qq0));
    atomicMin(&rowmin[gr + 1], fkey32(b1 + qq1));
    atomicMin(&rowmin[gr + 2], fkey32(b2 + qq2));
    atomicMin(&rowmin[gr + 3], fkey32(b3 + qq3));

  } else if (blk < 1024) {
    // ------- cham_col: gt points vs up/off candidates -------
    int blk2 = blk - 512;
    int qb = blk2 >> 4;          // [0,32)
    int seg = blk2 & 15;         // [0,16)
    int which = qb >> 4;         // 0=off, 1=up
    int b = (qb >> 2) & 3;
    int m0 = (qb & 3) * 1024 + tid * 4;   // [0,4096)
    const float* src = which ? up : off;
    if (tid < 128) {
      const float* sb = src + (size_t)b * NUU * 3 + (size_t)seg * 512 * 3;
      int i0 = tid * 4;
      const float4* s4 = (const float4*)(sb + (size_t)i0 * 3);
      float4 u0 = s4[0], u1 = s4[1], u2 = s4[2];
      sc[i0] = make_float4(u0.x, u0.y, u0.z,
                           fmaf(u0.x, u0.x, fmaf(u0.y, u0.y, u0.z * u0.z)));
      sc[i0 + 1] = make_float4(u0.w, u1.x, u1.y,
                               fmaf(u0.w, u0.w, fmaf(u1.x, u1.x, u1.y * u1.y)));
      sc[i0 + 2] = make_float4(u1.z, u1.w, u2.x,
                               fmaf(u1.z, u1.z, fmaf(u1.w, u1.w, u2.x * u2.x)));
      sc[i0 + 3] = make_float4(u2.y, u2.z, u2.w,
                               fmaf(u2.y, u2.y, fmaf(u2.z, u2.z, u2.w * u2.w)));
    }
    const float* g = gt + (size_t)b * NGG * 6 + (size_t)m0 * 6;
    float q0x = g[0],  q0y = g[1],  q0z = g[2];
    float q1x = g[6],  q1y = g[7],  q1z = g[8];
    float q2x = g[12], q2y = g[13], q2z = g[14];
    float q3x = g[18], q3y = g[19], q3z = g[20];
    float qq0 = fmaf(q0x, q0x, fmaf(q0y, q0y, q0z * q0z));
    float qq1 = fmaf(q1x, q1x, fmaf(q1y, q1y, q1z * q1z));
    float qq2 = fmaf(q2x, q2x, fmaf(q2y, q2y, q2z * q2z));
    float qq3 = fmaf(q3x, q3x, fmaf(q3y, q3y, q3z * q3z));
    float a0x = -2.f * q0x, a0y = -2.f * q0y, a0z = -2.f * q0z;
    float a1x = -2.f * q1x, a1y = -2.f * q1y, a1z = -2.f * q1z;
    float a2x = -2.f * q2x, a2y = -2.f * q2y, a2z = -2.f * q2z;
    float a3x = -2.f * q3x, a3y = -2.f * q3y, a3z = -2.f * q3z;
    __syncthreads();
    float b0 = 3.4e38f, b1 = 3.4e38f, b2 = 3.4e38f, b3 = 3.4e38f;
#pragma unroll 4
    for (int j = 0; j < 512; ++j) {
      float4 c = sc[j];
      float t;
      t = fmaf(c.x, a0x, c.w); t = fmaf(c.y, a0y, t); t = fmaf(c.z, a0z, t); b0 = fminf(b0, t);
      t = fmaf(c.x, a1x, c.w); t = fmaf(c.y, a1y, t); t = fmaf(c.z, a1z, t); b1 = fminf(b1, t);
      t = fmaf(c.x, a2x, c.w); t = fmaf(c.y, a2y, t); t = fmaf(c.z, a2z, t); b2 = fminf(b2, t);
      t = fmaf(c.x, a3x, c.w); t = fmaf(c.y, a3y, t); t = fmaf(c.z, a3z, t); b3 = fminf(b3, t);
    }
    int gc = which * 16384 + b * NGG + m0;
    atomicMin(&colmin[gc + 0], fkey32(b0 + qq0));
    atomicMin(&colmin[gc + 1], fkey32(b1 + qq1));
    atomicMin(&colmin[gc + 2], fkey32(b2 + qq2));
    atomicMin(&colmin[gc + 3], fkey32(b3 + qq3));

  } else {
    // ------- argmin: pts vs gt candidates (keyed: dist<<32 | idx) -------
    int blk3 = blk - 1024;
    int qb = blk3 >> 4;          // [0,16)
    int seg = blk3 & 15;         // [0,16), 256 candidates each
    int b = qb >> 2;
    int m0 = (qb & 3) * 1024 + tid * 4;   // [0,4096)
    if (tid < 128) {
      const float* gtb = gt + (size_t)b * NGG * 6 + (size_t)seg * 256 * 6;
      int i0 = tid * 2;
      const float4* g4 = (const float4*)(gtb + (size_t)i0 * 6);
      float4 u0 = g4[0], u1 = g4[1], u2 = g4[2];
      sc[i0] = make_float4(u0.x, u0.y, u0.z,
                           fmaf(u0.x, u0.x, fmaf(u0.y, u0.y, u0.z * u0.z)));
      sc[i0 + 1] = make_float4(u1.z, u1.w, u2.x,
                               fmaf(u1.z, u1.z, fmaf(u1.w, u1.w, u2.x * u2.x)));
    }
    size_t fb = ((size_t)(b * NN + m0) * 3) >> 2;
    const float4* p4 = (const float4*)pts;
    float4 A = p4[fb], B = p4[fb + 1], C = p4[fb + 2];
    float q0x = A.x, q0y = A.y, q0z = A.z;
    float q1x = A.w, q1y = B.x, q1z = B.y;
    float q2x = B.z, q2y = B.w, q2z = C.x;
    float q3x = C.y, q3y = C.z, q3z = C.w;
    float a0x = -2.f * q0x, a0y = -2.f * q0y, a0z = -2.f * q0z;
    float a1x = -2.f * q1x, a1y = -2.f * q1y, a1z = -2.f * q1z;
    float a2x = -2.f * q2x, a2y = -2.f * q2y, a2z = -2.f * q2z;
    float a3x = -2.f * q3x, a3y = -2.f * q3y, a3z = -2.f * q3z;
    __syncthreads();
    float b0 = 3.4e38f, b1 = 3.4e38f, b2 = 3.4e38f, b3 = 3.4e38f;
    int i0 = 0, i1 = 0, i2 = 0, i3 = 0;
#pragma unroll 4
    for (int j = 0; j < 256; ++j) {
      float4 c = sc[j];
      float t; bool cc;
      t = fmaf(c.x, a0x, c.w); t = fmaf(c.y, a0y, t); t = fmaf(c.z, a0z, t);
      cc = t < b0; b0 = cc ? t : b0; i0 = cc ? j : i0;
      t = fmaf(c.x, a1x, c.w); t = fmaf(c.y, a1y, t); t = fmaf(c.z, a1z, t);
      cc = t < b1; b1 = cc ? t : b1; i1 = cc ? j : i1;
      t = fmaf(c.x, a2x, c.w); t = fmaf(c.y, a2y, t); t = fmaf(c.z, a2z, t);
      cc = t < b2; b2 = cc ? t : b2; i2 = cc ? j : i2;
      t = fmaf(c.x, a3x, c.w); t = fmaf(c.y, a3y, t); t = fmaf(c.z, a3z, t);
      cc = t < b3; b3 = cc ? t : b3; i3 = cc ? j : i3;
    }
    int q = b * NN + m0;
    int base = seg * 256;
    atomicMin(&keys[q + 0], ((unsigned long long)fkey32(b0) << 32) | (unsigned)(base + i0));
    atomicMin(&keys[q + 1], ((unsigned long long)fkey32(b1) << 32) | (unsigned)(base + i1));
    atomicMin(&keys[q + 2], ((unsigned long long)fkey32(b2) << 32) | (unsigned)(base + i2));
    atomicMin(&keys[q + 3], ((unsigned long long)fkey32(b3) << 32) | (unsigned)(base + i3));
  }
}

// ------------- fused: postgather (blocks 0..63) + reduce mins (64..447) -
__global__ __launch_bounds__(256) void k_post(
    const float* __restrict__ ori_pre, const float* __restrict__ nor_pre,
    const float* __restrict__ gt, const unsigned long long* __restrict__ keys,
    const unsigned* __restrict__ rowmin, const unsigned* __restrict__ colmin,
    float* __restrict__ nor_gt, float* __restrict__ ori_pro, float* __restrict__ acc) {
  __shared__ float sb1[4], sb2[4];
  int blk = blockIdx.x;
  if (blk < 64) {
    int q = blk * 256 + threadIdx.x;
    int b = q >> 12;
    float ox = ori_pre[q * 3 + 0], oy = ori_pre[q * 3 + 1], oz = ori_pre[q * 3 + 2];
    float n1 = sqrtf(fmaf(ox, ox, fmaf(oy, oy, oz * oz)) + 1e-8f) + 1e-10f;
    ox /= n1; oy /= n1; oz /= n1;
    float px = nor_pre[q * 3 + 0], py = nor_pre[q * 3 + 1], pz = nor_pre[q * 3 + 2];
    float n2 = sqrtf(fmaf(px, px, fmaf(py, py, pz * pz)) + 1e-8f) + 1e-10f;
    px /= n2; py /= n2; pz /= n2;
    unsigned idx = (unsigned)(keys[q] & 0xffffffffULL);
    const float* g = gt + (size_t)b * NGG * 6 + (size_t)idx * 6 + 3;
    float gx = g[0], gy = g[1], gz = g[2];
    float dn = fmaf(gx, ox, fmaf(gy, oy, gz * oz));
    float vx = ox - gx * dn, vy = oy - gy * dn, vz = oz - gz * dn;
    float n3 = sqrtf(fmaf(vx, vx, fmaf(vy, vy, vz * vz)) + 1e-8f) + 1e-10f;
    vx /= n3; vy /= n3; vz /= n3;
    nor_gt[q * 3 + 0] = gx; nor_gt[q * 3 + 1] = gy; nor_gt[q * 3 + 2] = gz;
    ori_pro[q * 3 + 0] = vx; ori_pro[q * 3 + 1] = vy; ori_pro[q * 3 + 2] = vz;
    float na = fmaxf(sqrtf(fmaf(gx, gx, fmaf(gy, gy, gz * gz))), 1e-8f);
    float nb = fmaxf(sqrtf(fmaf(px, px, fmaf(py, py, pz * pz))), 1e-8f);
    float cs = fmaf(gx, px, fmaf(gy, py, gz * pz)) / (na * nb);
    float t_nor = 1.f - fabsf(cs);
    float t_ori = fabsf(dn);
    float s1 = block_sum_256(t_nor, sb1);
    float s2 = block_sum_256(t_ori, sb2);
    if (threadIdx.x == 0) {
      atomicAdd(&acc[1], s1);
      atomicAdd(&acc[2], s2);
    }
  } else {
    int rblk = blk - 64;   // [0,384)
    float v;
    int slot;
    if (rblk < 256) {
      int i = rblk * 256 + threadIdx.x;
      v = unfkey32(rowmin[i]);
      slot = (i >> 15) ? 5 : 3;   // 0=offset rows -> acc3, 1=up rows -> acc5
    } else {
      int i = (rblk - 256) * 256 + threadIdx.x;
      v = unfkey32(colmin[i]);
      slot = (i >> 14) ? 6 : 4;   // 0=offset cols -> acc4, 1=up cols -> acc6
    }
    float s = block_sum_256(v, sb1);
    if (threadIdx.x == 0) atomicAdd(&acc[slot], s);
  }
}

// ------------- KNN (K=6) among pts + fused loss_smooth -----------------
// grid (512): 32 queries/block, 8 threads/query, interleaved candidates.
__global__ __launch_bounds__(256) void k_knn_smooth(const float* __restrict__ pts,
                                                    const float* __restrict__ nor_gt,
                                                    const float* __restrict__ ori_pro,
                                                    float* __restrict__ acc) {
  __shared__ float4 sp[4096];                             // 64 KB
  __shared__ unsigned long long marr[32 * 48];            // 12 KB
  __shared__ float sbuf[4];
  int q_local = threadIdx.x >> 3;
  int t = threadIdx.x & 7;
  int q = blockIdx.x * 32 + q_local;
  int b = q >> 12;
  int n = q & 4095;
  const float* pb = pts + (size_t)b * NN * 3;
  for (int p = threadIdx.x; p < 4096; p += 256) {
    float x = pb[p * 3 + 0], y = pb[p * 3 + 1], z = pb[p * 3 + 2];
    sp[p] = make_float4(x, y, z, fmaf(x, x, fmaf(y, y, z * z)));
  }
  __syncthreads();
  float4 qp = sp[n];
  float qx2 = -2.f * qp.x, qy2 = -2.f * qp.y, qz2 = -2.f * qp.z;
  float d0 = 3.4e38f, d1 = 3.4e38f, d2 = 3.4e38f,
        d3 = 3.4e38f, d4 = 3.4e38f, d5 = 3.4e38f;
  int i0 = 0, i1 = 0, i2 = 0, i3 = 0, i4 = 0, i5 = 0;
#pragma unroll 4
  for (int j = 0; j < 512; ++j) {
    int c = (j << 3) | t;    // interleaved: 8-lane-contiguous + broadcast
    float4 p = sp[c];
    float d = fmaf(p.x, qx2, p.w);
    d = fmaf(p.y, qy2, d);
    d = fmaf(p.z, qz2, d);
    if (d < d5) {            // rare: sorted insertion of (d, c)
      int ci = c;
      bool cc; float nd; int ni;
      cc = d < d0; nd = cc ? d : d0; d = cc ? d0 : d; ni = cc ? ci : i0; ci = cc ? i0 : ci; d0 = nd; i0 = ni;
      cc = d < d1; nd = cc ? d : d1; d = cc ? d1 : d; ni = cc ? ci : i1; ci = cc ? i1 : ci; d1 = nd; i1 = ni;
      cc = d < d2; nd = cc ? d : d2; d = cc ? d2 : d; ni = cc ? ci : i2; ci = cc ? i2 : ci; d2 = nd; i2 = ni;
      cc = d < d3; nd = cc ? d : d3; d = cc ? d3 : d; ni = cc ? ci : i3; ci = cc ? i3 : ci; d3 = nd; i3 = ni;
      cc = d < d4; nd = cc ? d : d4; d = cc ? d4 : d; ni = cc ? ci : i4; ci = cc ? i4 : ci; d4 = nd; i4 = ni;
      cc = d < d5; nd = cc ? d : d5;                    ni = cc ? ci : i5;                  d5 = nd; i5 = ni;
    }
  }
  unsigned long long* mq = &marr[q_local * 48 + t * 6];
  mq[0] = ((unsigned long long)fkey32(d0) << 32) | (unsigned)i0;
  mq[1] = ((unsigned long long)fkey32(d1) << 32) | (unsigned)i1;
  mq[2] = ((unsigned long long)fkey32(d2) << 32) | (unsigned)i2;
  mq[3] = ((unsigned long long)fkey32(d3) << 32) | (unsigned)i3;
  mq[4] = ((unsigned long long)fkey32(d4) << 32) | (unsigned)i4;
  mq[5] = ((unsigned long long)fkey32(d5) << 32) | (unsigned)i5;
  __syncthreads();
  float sum = 0.f;
  if (t == 0) {
    float ngx = nor_gt[q * 3 + 0], ngy = nor_gt[q * 3 + 1], ngz = nor_gt[q * 3 + 2];
    float box = ori_pro[q * 3 + 0], boy = ori_pro[q * 3 + 1], boz = ori_pro[q * 3 + 2];
    float rx = boy * ngz - boz * ngy;
    float ry = boz * ngx - box * ngz;
    float rz = box * ngy - boy * ngx;
    float nbo = fmaxf(sqrtf(fmaf(box, box, fmaf(boy, boy, boz * boz))), 1e-8f);
    float nrot = fmaxf(sqrtf(fmaf(rx, rx, fmaf(ry, ry, rz * rz))), 1e-8f);
    const unsigned long long* mrow = &marr[q_local * 48];
    int head[8] = {0, 0, 0, 0, 0, 0, 0, 0};
    for (int k = 0; k < 6; ++k) {
      unsigned long long best = ~0ULL;
      int bl = 0;
#pragma unroll
      for (int l = 0; l < 8; ++l) {
        unsigned long long v = mrow[l * 6 + head[l]];
        if (v < best) { best = v; bl = l; }
      }
#pragma unroll
      for (int l = 0; l < 8; ++l) head[l] += (l == bl) ? 1 : 0;
      int id = (int)(best & 0xffffffffULL);
      const float* gn = &nor_gt[(size_t)(b * 4096 + id) * 3];
      const float* go = &ori_pro[(size_t)(b * 4096 + id) * 3];
      float gnx = gn[0], gny = gn[1], gnz = gn[2];
      float gox = go[0], goy = go[1], goz = go[2];
      float nd = fmaf(gnx, ngx, fmaf(gny, ngy, gnz * ngz));
      float wv = (expf(-nd / 0.3f) * 10.f + 1.f) < 4.f ? 1.f : 5.f;
      float ngo = fmaxf(sqrtf(fmaf(gox, gox, fmaf(goy, goy, goz * goz))), 1e-8f);
      float c0 = fmaf(gox, box, fmaf(goy, boy, goz * boz)) / (ngo * nbo);
      float c1 = fmaf(gox, rx, fmaf(goy, ry, goz * rz)) / (ngo * nrot);
      float cosv = fminf(1.f - fabsf(c0), 1.f - fabsf(c1));
      sum += wv * cosv;
    }
  }
  float s = block_sum_256(sum, sbuf);
  if (threadIdx.x == 0) atomicAdd(&acc[0], s);
}

// ------------- combine to the 7 outputs --------------------------------
__global__ void k_finalize(const float* __restrict__ acc, float* __restrict__ out) {
  if (threadIdx.x == 0 && blockIdx.x == 0) {
    float loss_smooth = acc[0] / 98304.f;            // B*N*K
    float loss_nor = acc[1] / 16384.f;               // B*N
    float loss_nor_ori = acc[2] / 16384.f;
    float lco = acc[3] / 32768.f + acc[4] / 16384.f; // B*NU rows + B*NG cols
    float lc = acc[5] / 32768.f + acc[6] / 16384.f;
    float loss_cd = lc + 0.4f * lco;
    float loss = loss_smooth + loss_nor + 0.1f * loss_nor_ori + 200.f * loss_cd;
    out[0] = loss;
    out[1] = loss_smooth;
    out[2] = loss_nor;
    out[3] = lco;
    out[4] = loss_nor_ori;
    out[5] = lc;
    out[6] = lc;
  }
}

extern "C" void kernel_launch(void* const* d_in, const int* in_sizes, int n_in,
                              void* d_out, int out_size, void* d_ws, size_t ws_size,
                              hipStream_t stream) {
  (void)in_sizes; (void)n_in; (void)out_size; (void)ws_size;
  const float* ori_pre = (const float*)d_in[0];
  const float* nor_pre = (const float*)d_in[1];
  const float* xyz_up = (const float*)d_in[2];
  const float* xyz_off = (const float*)d_in[3];
  const float* pts = (const float*)d_in[4];
  const float* gt = (const float*)d_in[5];
  float* out = (float*)d_out;
  char* ws = (char*)d_ws;

  float* acc = (float*)(ws + 0);                                   // 16 floats
  unsigned long long* keys = (unsigned long long*)(ws + 512);      // 16384 u64 = 128 KB
  unsigned* rowmin = (unsigned*)(ws + 512 + 131072);               // 65536 u32 = 256 KB
  unsigned* colmin = (unsigned*)(ws + 512 + 131072 + 262144);      // 32768 u32 = 128 KB
  float* nor_gt = (float*)(ws + 512 + 131072 + 262144 + 131072);   // 49152 f32 = 192 KB
  float* ori_pro = (float*)(ws + 512 + 131072 + 262144 + 131072 + 196608);

  hipMemsetAsync(acc, 0, 64, stream);
  hipMemsetAsync(ws + 512, 0xFF, 131072 + 262144 + 131072, stream);

  k_scan<<<1280, 256, 0, stream>>>(pts, gt, xyz_up, xyz_off, keys, rowmin, colmin);
  k_post<<<448, 256, 0, stream>>>(ori_pre, nor_pre, gt, keys, rowmin, colmin,
                                  nor_gt, ori_pro, acc);
  k_knn_smooth<<<512, 256, 0, stream>>>(pts, nor_gt, ori_pro, acc);
  k_finalize<<<1, 64, 0, stream>>>(acc, out);
}